// Round 9
// baseline (127.238 us; speedup 1.0000x reference)
//
#include <hip/hip_runtime.h>
#include <hip/hip_bf16.h>

typedef short bf16x8 __attribute__((ext_vector_type(8)));
typedef float f32x4  __attribute__((ext_vector_type(4)));

#define KK    49
#define GCH   16
#define CIN   256
#define MID   64
#define NGRP  16
#define WID   56
#define HWSZ  3136
#define NB    4
#define NPIX  12544
#define EPSV  1e-5f

// ws float-offsets
#define WS_SUM   0                     // 128 f32: sum/sumsq
#define WS_W1BF  128                   // w1 bf16 [64][256]   = 8192 f32
#define WS_W2BF  8320                  // w2 bf16 [16][64][64] = 32768 f32 (rows 49..63 zero)
#define WS_T     41088                 // t bf16 [64][NPIX]   = 401408 f32
#define WS_XI    442496                // xi f32 [B][G][HW][16] = 3211264 f32
#define WS_XI_END 3653760              // total f32 if xi used (~14.6 MB)

__device__ inline unsigned short f2bf(float f) {
    __hip_bfloat16 h = __float2bfloat16(f);
    return *reinterpret_cast<unsigned short*>(&h);
}
__device__ inline float bf2f(unsigned short s) {
    return __uint_as_float(((unsigned)s) << 16);
}
__device__ inline unsigned pack2(float lo, float hi) {
    return ((unsigned)f2bf(hi) << 16) | (unsigned)f2bf(lo);
}

// ---- kA: pack weights to bf16; optionally repack x channel-interleaved ----
__global__ __launch_bounds__(256) void kA_pack(const float* __restrict__ x,
                                               const float* __restrict__ w1,
                                               const float* __restrict__ w2,
                                               float* __restrict__ ws) {
    const int bid = blockIdx.x;
    if (bid < 64) {                       // w1bf[mid][c] (same layout as w1)
        const int i = bid * 256 + threadIdx.x;          // [0,16384)
        ((unsigned short*)(ws + WS_W1BF))[i] = f2bf(w1[i]);
    } else if (bid < 320) {               // w2bf[g][row(64)][k=mid]
        const int i = (bid - 64) * 256 + threadIdx.x;   // [0,65536)
        const int g = i >> 12, row = (i >> 6) & 63, k = i & 63;
        const float v = (row < KK) ? w2[((size_t)(g * KK + row)) * MID + k] : 0.f;
        ((unsigned short*)(ws + WS_W2BF))[i] = f2bf(v);
    } else {                              // xi[(b,g,hw)][16ch] f32
        const int pg = (bid - 320) * 256 + threadIdx.x; // [0,200704)
        const int b   = pg / (NGRP * HWSZ);
        const int rem = pg - b * NGRP * HWSZ;
        const int g   = rem / HWSZ;
        const int hw  = rem - g * HWSZ;
        const float* xs = x + ((size_t)(b * CIN + g * GCH)) * HWSZ + hw;
        float v[16];
#pragma unroll
        for (int i = 0; i < 16; ++i) v[i] = xs[(size_t)i * HWSZ];  // coalesced
        float4* dst = (float4*)(ws + WS_XI + (size_t)pg * 16);
        dst[0] = make_float4(v[0], v[1], v[2], v[3]);
        dst[1] = make_float4(v[4], v[5], v[6], v[7]);
        dst[2] = make_float4(v[8], v[9], v[10], v[11]);
        dst[3] = make_float4(v[12], v[13], v[14], v[15]);
    }
}

// ---- kB: conv1 as bf16 MFMA GEMM + batch stats; t stored bf16 plane-major ----
// 64-px blocks (3136/64=49 exact -> b uniform). Fragment pattern verified in R8:
// A=[row][k] af=A[m*16+r][ks*32+hi*8]; B=[px][k]; D: col=lane&15(px), row=hi*4+j.
__global__ __launch_bounds__(256) void kB_conv1(const float* __restrict__ x,
                                                const float* __restrict__ b1,
                                                float* __restrict__ ws) {
    __shared__ unsigned short xtb[64][266];   // [px][k] pad: 133 dwords (odd)
    __shared__ unsigned short w1b[64][266];   // [mid][k]
    const int tid  = threadIdx.x;
    const int lane = tid & 63, r = lane & 15, hi = lane >> 4;
    const int wave = tid >> 6;                // m-tile 0..3
    const int pix0 = blockIdx.x * 64;
    const int b    = pix0 / HWSZ;
    const int hw0  = pix0 - b * HWSZ;

    // stage w1 bf16 -> LDS (padded rows)
    {
        const unsigned short* w1bf = (const unsigned short*)(ws + WS_W1BF);
#pragma unroll
        for (int e = tid; e < 2048; e += 256) {   // chunks of 8 shorts
            const int row = e >> 5, c8 = (e & 31) * 8;
            *(bf16x8*)&w1b[row][c8] = *(const bf16x8*)(w1bf + row * 256 + c8);
        }
    }
    // stage x -> bf16 [px][k]
    {
        const int px = tid & 63;
        const int ks = tid >> 6;
        const float* xs = x + (size_t)b * CIN * HWSZ + hw0 + px;
#pragma unroll
        for (int pass = 0; pass < 8; ++pass) {
            const int k0 = pass * 32 + ks * 8;
            unsigned pk[4];
#pragma unroll
            for (int u = 0; u < 4; ++u)
                pk[u] = pack2(xs[(size_t)(k0 + 2 * u) * HWSZ],
                              xs[(size_t)(k0 + 2 * u + 1) * HWSZ]);
            *(bf16x8*)&xtb[px][k0] = *(bf16x8*)pk;
        }
    }
    __syncthreads();

    // MFMA: wave m covers mids m*16..+16, all 4 n-tiles, K=256
    const float4 bv = *(const float4*)(b1 + wave * 16 + hi * 4);
    f32x4 acc[4];
#pragma unroll
    for (int ni = 0; ni < 4; ++ni) { acc[ni][0]=bv.x; acc[ni][1]=bv.y; acc[ni][2]=bv.z; acc[ni][3]=bv.w; }
#pragma unroll
    for (int ks = 0; ks < 8; ++ks) {
        const bf16x8 af = *(const bf16x8*)&w1b[wave * 16 + r][ks * 32 + hi * 8];
#pragma unroll
        for (int ni = 0; ni < 4; ++ni) {
            const bf16x8 bfv = *(const bf16x8*)&xtb[ni * 16 + r][ks * 32 + hi * 8];
            acc[ni] = __builtin_amdgcn_mfma_f32_16x16x32_bf16(af, bfv, acc[ni], 0, 0, 0);
        }
    }

    // t store (bf16) + stats (f32, exact from acc)
    unsigned short* tws = (unsigned short*)(ws + WS_T);
#pragma unroll
    for (int j = 0; j < 4; ++j) {
        const int mid = wave * 16 + hi * 4 + j;
        float s = 0.f, qq = 0.f;
#pragma unroll
        for (int ni = 0; ni < 4; ++ni) {
            const float v = acc[ni][j];
            tws[(size_t)mid * NPIX + pix0 + ni * 16 + r] = f2bf(v);
            s += v; qq += v * v;
        }
#pragma unroll
        for (int m = 1; m < 16; m <<= 1) {
            s  += __shfl_xor(s, m, 64);
            qq += __shfl_xor(qq, m, 64);
        }
        if (r == 0) {
            atomicAdd(&ws[WS_SUM + mid],      s);
            atomicAdd(&ws[WS_SUM + 64 + mid], qq);
        }
    }
}

// ---- kC: BN+ReLU -> conv2 (MFMA) -> involution. 64 px x 1 group per block ----
template <int USE_XI>
__global__ __launch_bounds__(256) void kC_fused(const float* __restrict__ x,
                                                const float* __restrict__ b2,
                                                const float* __restrict__ gamma,
                                                const float* __restrict__ beta,
                                                const float* __restrict__ ws,
                                                float* __restrict__ out) {
    __shared__ char lbuf[18944];
    __shared__ float a_s[64], c_s[64];
    unsigned short (*tlb)[74] = (unsigned short(*)[74])lbuf;            // [px][k] 9472 B
    unsigned short (*wb)[74]  = (unsigned short(*)[74])(lbuf + 9472);   // [tap][k] 9472 B
    float (*swgt)[53]         = (float(*)[53])lbuf;                     // [px][tap] 13568 B (post-MFMA overlay)

    const int tid  = threadIdx.x;
    const int lane = tid & 63, r = lane & 15, hi = lane >> 4;
    const int wave = tid >> 6;
    const int q    = __builtin_amdgcn_readfirstlane(wave);  // slot: m-tile & channel quad
    const int px   = tid & 63;
    const int pix0 = blockIdx.x * 64;                       // b, hw0 uniform (49 blocks/batch)
    const int g    = blockIdx.y;
    const int b    = pix0 / HWSZ;
    const int hw0  = pix0 - b * HWSZ;

    if (tid < 64) {                                         // BN coefs
        const float n   = (float)NPIX;
        const float mu  = ws[WS_SUM + tid] / n;
        const float var = ws[WS_SUM + 64 + tid] / n - mu * mu;
        const float a   = gamma[tid] * rsqrtf(var + EPSV);
        a_s[tid] = a;
        c_s[tid] = beta[tid] - mu * a;
    }
    __syncthreads();

    // stage T: BN+ReLU(bf16 t) -> tlb[px][k], thread covers k = q*16..+16
    {
        const unsigned short* tws = (const unsigned short*)(ws + WS_T);
        unsigned pk[8];
#pragma unroll
        for (int u = 0; u < 8; ++u) {
            const int k = q * 16 + 2 * u;
            float v0 = bf2f(tws[(size_t)k * NPIX + pix0 + px]);
            float v1 = bf2f(tws[(size_t)(k + 1) * NPIX + pix0 + px]);
            v0 = fmaxf(0.f, fmaf(a_s[k], v0, c_s[k]));
            v1 = fmaxf(0.f, fmaf(a_s[k + 1], v1, c_s[k + 1]));
            pk[u] = pack2(v0, v1);
        }
        *(bf16x8*)&tlb[px][q * 16]     = *(bf16x8*)&pk[0];
        *(bf16x8*)&tlb[px][q * 16 + 8] = *(bf16x8*)&pk[4];
    }
    // stage W2 bf16 -> wb[tap][k]
    {
        const unsigned short* src = (const unsigned short*)(ws + WS_W2BF) + (size_t)g * 4096;
#pragma unroll
        for (int e = tid; e < 512; e += 256) {
            const int row = e >> 3, c8 = (e & 7) * 8;
            *(bf16x8*)&wb[row][c8] = *(const bf16x8*)(src + row * 64 + c8);
        }
    }
    __syncthreads();

    // MFMA: wave = m-tile (taps), 4 n-tiles, K=64 (2 k-steps)
    f32x4 acc[4] = {{0,0,0,0},{0,0,0,0},{0,0,0,0},{0,0,0,0}};
#pragma unroll
    for (int ks = 0; ks < 2; ++ks) {
        const bf16x8 af = *(const bf16x8*)&wb[wave * 16 + r][ks * 32 + hi * 8];
#pragma unroll
        for (int ni = 0; ni < 4; ++ni) {
            const bf16x8 bfv = *(const bf16x8*)&tlb[ni * 16 + r][ks * 32 + hi * 8];
            acc[ni] = __builtin_amdgcn_mfma_f32_16x16x32_bf16(af, bfv, acc[ni], 0, 0, 0);
        }
    }
    __syncthreads();                                         // tlb/wb reads done
#pragma unroll
    for (int ni = 0; ni < 4; ++ni)
#pragma unroll
        for (int j = 0; j < 4; ++j) {
            const int tap = wave * 16 + hi * 4 + j;
            if (tap < KK) swgt[ni * 16 + r][tap] = acc[ni][j];
        }
    __syncthreads();

    // Phase B: involution; slot q -> channels q*4..+3
    const int hw = hw0 + px;
    const int h  = hw / WID, w = hw - h * WID;
    const float* b2g = b2 + g * KK;
    float a0 = 0.f, a1 = 0.f, a2 = 0.f, a3 = 0.f;

    const float* xb4 = USE_XI ? (ws + WS_XI + ((size_t)(b * NGRP + g) * HWSZ) * 16 + q * 4)
                              : (x + ((size_t)(b * CIN + g * GCH + q * 4)) * HWSZ);
#pragma unroll
    for (int r7 = 0; r7 < 7; ++r7) {
        const bool rowok = (unsigned)(h + r7 - 3) < 56u;
        const int  roff  = hw + (r7 - 3) * WID - 3;
#pragma unroll
        for (int j = 0; j < 7; ++j) {
            const int   t   = r7 * 7 + j;
            const float wgv = swgt[px][t] + b2g[t];
            const bool  ok  = rowok && ((unsigned)(w + j - 3) < 56u);
            const float wm  = ok ? wgv : 0.f;
            int idx = roff + j;
            idx = idx < 0 ? 0 : (idx > HWSZ - 1 ? HWSZ - 1 : idx);
            if (USE_XI) {
                const float4 xv = *(const float4*)(xb4 + (size_t)idx * 16);
                a0 = fmaf(wm, xv.x, a0);
                a1 = fmaf(wm, xv.y, a1);
                a2 = fmaf(wm, xv.z, a2);
                a3 = fmaf(wm, xv.w, a3);
            } else {
                a0 = fmaf(wm, xb4[idx],            a0);
                a1 = fmaf(wm, xb4[idx + HWSZ],     a1);
                a2 = fmaf(wm, xb4[idx + 2 * HWSZ], a2);
                a3 = fmaf(wm, xb4[idx + 3 * HWSZ], a3);
            }
        }
    }

    float* ob = out + ((size_t)(b * CIN + g * GCH + q * 4)) * HWSZ + hw;
    ob[0]        = a0;
    ob[HWSZ]     = a1;
    ob[2 * HWSZ] = a2;
    ob[3 * HWSZ] = a3;
}

extern "C" void kernel_launch(void* const* d_in, const int* in_sizes, int n_in,
                              void* d_out, int out_size, void* d_ws, size_t ws_size,
                              hipStream_t stream) {
    const float* x     = (const float*)d_in[0];
    const float* w1    = (const float*)d_in[1];
    const float* b1    = (const float*)d_in[2];
    const float* gamma = (const float*)d_in[3];
    const float* beta  = (const float*)d_in[4];
    const float* w2    = (const float*)d_in[5];
    const float* b2    = (const float*)d_in[6];
    float* out = (float*)d_out;
    float* ws  = (float*)d_ws;

    const bool use_xi = ws_size >= (size_t)WS_XI_END * sizeof(float);

    hipMemsetAsync(ws, 0, 128 * sizeof(float), stream);
    kA_pack<<<use_xi ? 1104 : 320, 256, 0, stream>>>(x, w1, w2, ws);
    kB_conv1<<<196, 256, 0, stream>>>(x, b1, ws);
    if (use_xi)
        kC_fused<1><<<dim3(196, 16), 256, 0, stream>>>(x, b2, gamma, beta, ws, out);
    else
        kC_fused<0><<<dim3(196, 16), 256, 0, stream>>>(x, b2, gamma, beta, ws, out);
}